// Round 8
// baseline (343.515 us; speedup 1.0000x reference)
//
#include <hip/hip_runtime.h>
#include <math.h>

// Problem constants (from reference)
#define BB 4
#define NN 1024
#define EE 1024
#define HH 16
#define DD 64
#define MAXLEN 512
#define EPS 1e-5f

typedef __attribute__((ext_vector_type(8))) __bf16 bf16x8;
typedef __attribute__((ext_vector_type(4))) float floatx4;
typedef __attribute__((ext_vector_type(8))) unsigned short ushort8;

#define SWAIT(s) asm volatile("s_waitcnt " s ::: "memory")
#define SCHEDBAR() __builtin_amdgcn_sched_barrier(0)

__device__ __forceinline__ unsigned short f2bf(float f) {
    unsigned u = __float_as_uint(f);
    u += 0x7fffu + ((u >> 16) & 1u);   // RNE
    return (unsigned short)(u >> 16);
}

// counted vmcnt wait: rem = number of 4-load tile-groups allowed to remain
// in flight. Literal-string dispatch (s_waitcnt imm must be a literal).
template <int MAXR>
__device__ __forceinline__ void vm_wait_rt(int rem) {
    if (rem >= MAXR) {
        if constexpr (MAXR <= 0)      SWAIT("vmcnt(0)");
        else if constexpr (MAXR == 1) SWAIT("vmcnt(4)");
        else if constexpr (MAXR == 2) SWAIT("vmcnt(8)");
        else                          SWAIT("vmcnt(12)");
        return;
    }
    if (rem <= 0) { SWAIT("vmcnt(0)"); return; }
    if (rem == 1) { SWAIT("vmcnt(4)"); return; }
    if constexpr (MAXR >= 3) { if (rem == 2) { SWAIT("vmcnt(8)");  return; } }
}

// ---------------------------------------------------------------------------
// fp32 -> bf16 for all four weight matrices in ONE launch (4 segments).
// ---------------------------------------------------------------------------
__global__ __launch_bounds__(256) void f2bf_all_kernel(
    const float* __restrict__ s0, const float* __restrict__ s1,
    const float* __restrict__ s2, const float* __restrict__ s3,
    unsigned short* __restrict__ d0, unsigned short* __restrict__ d1,
    unsigned short* __restrict__ d2, unsigned short* __restrict__ d3) {
    const int C0 = 3 * EE * EE / 4;            // 786432
    const int C1 = C0 + EE * EE / 4;           // 1048576
    const int C2 = C1 + EE * EE;               // 2097152
    int i = blockIdx.x * 256 + threadIdx.x;
    const float* in; unsigned short* out; int j;
    if (i < C0)      { in = s0; out = d0; j = i; }
    else if (i < C1) { in = s1; out = d1; j = i - C0; }
    else if (i < C2) { in = s2; out = d2; j = i - C1; }
    else             { in = s3; out = d3; j = i - C2; }
    float4 v = ((const float4*)in)[j];
    ushort4 o;
    o.x = f2bf(v.x); o.y = f2bf(v.y); o.z = f2bf(v.z); o.w = f2bf(v.w);
    ((ushort4*)out)[j] = o;
}

// ---------------------------------------------------------------------------
// out += p  (split-K partial reduction; vectorized by 4)
// ---------------------------------------------------------------------------
__global__ __launch_bounds__(256) void addp_kernel(float* __restrict__ out,
                                                   const float* __restrict__ p) {
    const int i = blockIdx.x * 256 + threadIdx.x;
    float4 a = ((float4*)out)[i];
    const float4 b = ((const float4*)p)[i];
    a.x += b.x; a.y += b.y; a.z += b.z; a.w += b.w;
    ((float4*)out)[i] = a;
}

// ---------------------------------------------------------------------------
// LayerNorm: one block per row of E=1024; float4 loads; bf16 ushort4 output.
// ---------------------------------------------------------------------------
__global__ __launch_bounds__(256) void ln_kernel(const float* __restrict__ x,
                                                 const float* __restrict__ g,
                                                 const float* __restrict__ b,
                                                 unsigned short* __restrict__ out) {
    const int row = blockIdx.x;
    const int tid = threadIdx.x;
    const float4 v = ((const float4*)(x + (size_t)row * EE))[tid];
    float s  = v.x + v.y + v.z + v.w;
    float s2 = v.x * v.x + v.y * v.y + v.z * v.z + v.w * v.w;
    for (int off = 32; off > 0; off >>= 1) {
        s  += __shfl_xor(s, off);
        s2 += __shfl_xor(s2, off);
    }
    __shared__ float red[8];
    const int wave = tid >> 6, lane = tid & 63;
    if (lane == 0) { red[wave] = s; red[4 + wave] = s2; }
    __syncthreads();
    s  = red[0] + red[1] + red[2] + red[3];
    s2 = red[4] + red[5] + red[6] + red[7];
    const float mu  = s * (1.0f / EE);
    const float var = s2 * (1.0f / EE) - mu * mu;
    const float inv = rsqrtf(var + EPS);
    const float4 gv = ((const float4*)g)[tid];
    const float4 bv = ((const float4*)b)[tid];
    ushort4 o;
    o.x = f2bf((v.x - mu) * inv * gv.x + bv.x);
    o.y = f2bf((v.y - mu) * inv * gv.y + bv.y);
    o.z = f2bf((v.z - mu) * inv * gv.z + bv.z);
    o.w = f2bf((v.w - mu) * inv * gv.w + bv.w);
    ((ushort4*)(out + (size_t)row * EE))[tid] = o;
}

// ---------------------------------------------------------------------------
// m97-style TLP GEMM: 128x128 tile, 4 waves (64x64 each), ring-2 BK=32
// buffers (32 KB LDS) -> 3 blocks/CU (12 waves). Counted vmcnt(4); tile t+2
// staged at the TAIL of body t (trailing barrier seals WAR). Compiler manages
// lgkmcnt. Both-sides swizzle. XCD chunk swizzle (grid %8 == 0).
// VARIANT: 0 = bias + bf16 out; 1 = bias + relu + bf16 out.
// ---------------------------------------------------------------------------
template <int VARIANT>
__global__ __launch_bounds__(256, 3) void gemm97t_kernel(
    const unsigned short* __restrict__ A,
    const unsigned short* __restrict__ W,
    const float* __restrict__ bias,
    void* __restrict__ Cout, int Nc, int K) {
    __shared__ unsigned short smem[2][8192];

    const int tid  = threadIdx.x;
    const int lane = tid & 63;
    const int wv   = tid >> 6;          // 0..3
    const int wm   = wv >> 1;
    const int wn   = wv & 1;

    int bx = blockIdx.x, by = blockIdx.y;
    {   // bijective XCD chunk swizzle (grid %8 == 0)
        const int gx  = gridDim.x;
        const int nwg = gx * gridDim.y;
        const int lin = by * gx + bx;
        const int sl  = (lin & 7) * (nwg >> 3) + (lin >> 3);
        bx = sl % gx; by = sl / gx;
    }
    const int row0 = by * 128;
    const int col0 = bx * 128;
    const int NT   = K >> 5;

    const int srow = lane >> 2;
    const int sq   = ((lane & 3) ^ ((lane >> 3) & 3)) * 8;   // elems
    const unsigned short* Ag = A + (size_t)(row0 + srow) * K + sq;
    const unsigned short* Wg = W + (size_t)(col0 + srow) * K + sq;

    auto stage = [&](int t) {
        unsigned short* dst = &smem[t & 1][0];
#pragma unroll
        for (int s = 0; s < 2; ++s) {
            const int r = (wv + s * 4) * 16;
            __builtin_amdgcn_global_load_lds(
                (const __attribute__((address_space(1))) unsigned int*)(Ag + (size_t)r * K + t * 32),
                (__attribute__((address_space(3))) unsigned int*)(dst + r * 32), 16, 0, 0);
        }
#pragma unroll
        for (int s = 0; s < 2; ++s) {
            const int r = (wv + s * 4) * 16;
            __builtin_amdgcn_global_load_lds(
                (const __attribute__((address_space(1))) unsigned int*)(Wg + (size_t)r * K + t * 32),
                (__attribute__((address_space(3))) unsigned int*)(dst + 4096 + r * 32), 16, 0, 0);
        }
    };

    const int frow = lane & 15;
    const int quad = lane >> 4;
    const int rq   = (quad ^ ((frow >> 1) & 3)) * 8;
    const int abase = (wm * 64 + frow) * 32 + rq;
    const int bbase = 4096 + (wn * 64 + frow) * 32 + rq;

    floatx4 acc[4][4];
#pragma unroll
    for (int m = 0; m < 4; ++m)
#pragma unroll
        for (int n = 0; n < 4; ++n) acc[m][n] = (floatx4){0.f, 0.f, 0.f, 0.f};

    stage(0); stage(1);

    for (int t = 0; t < NT; ++t) {
        if (t == NT - 1) { SWAIT("vmcnt(0)"); } else { SWAIT("vmcnt(4)"); }
        __builtin_amdgcn_s_barrier();
        SCHEDBAR();

        const unsigned short* buf = &smem[t & 1][0];
        bf16x8 af0 = *(const bf16x8*)(buf + abase);
        bf16x8 af1 = *(const bf16x8*)(buf + abase + 512);
        bf16x8 af2 = *(const bf16x8*)(buf + abase + 1024);
        bf16x8 af3 = *(const bf16x8*)(buf + abase + 1536);
        bf16x8 bf0 = *(const bf16x8*)(buf + bbase);
        bf16x8 bf1 = *(const bf16x8*)(buf + bbase + 512);
        bf16x8 bf2 = *(const bf16x8*)(buf + bbase + 1024);
        bf16x8 bf3 = *(const bf16x8*)(buf + bbase + 1536);

        __builtin_amdgcn_s_setprio(1);
#pragma unroll
        for (int m = 0; m < 4; ++m)
            acc[m][0] = __builtin_amdgcn_mfma_f32_16x16x32_bf16(
                (m == 0 ? af0 : m == 1 ? af1 : m == 2 ? af2 : af3), bf0, acc[m][0], 0, 0, 0);
#pragma unroll
        for (int m = 0; m < 4; ++m)
            acc[m][1] = __builtin_amdgcn_mfma_f32_16x16x32_bf16(
                (m == 0 ? af0 : m == 1 ? af1 : m == 2 ? af2 : af3), bf1, acc[m][1], 0, 0, 0);
#pragma unroll
        for (int m = 0; m < 4; ++m)
            acc[m][2] = __builtin_amdgcn_mfma_f32_16x16x32_bf16(
                (m == 0 ? af0 : m == 1 ? af1 : m == 2 ? af2 : af3), bf2, acc[m][2], 0, 0, 0);
#pragma unroll
        for (int m = 0; m < 4; ++m)
            acc[m][3] = __builtin_amdgcn_mfma_f32_16x16x32_bf16(
                (m == 0 ? af0 : m == 1 ? af1 : m == 2 ? af2 : af3), bf3, acc[m][3], 0, 0, 0);
        __builtin_amdgcn_s_setprio(0);
        SCHEDBAR();
        __builtin_amdgcn_s_barrier();
        SCHEDBAR();
        if (t + 2 < NT) stage(t + 2);
        SCHEDBAR();
    }

    unsigned short* Cb = (unsigned short*)Cout;
    const int crow = (lane >> 4) * 4;
    const int ccol = lane & 15;
#pragma unroll
    for (int n = 0; n < 4; ++n) {
        const int nn = col0 + wn * 64 + n * 16 + ccol;
        const float bv = bias[nn];
#pragma unroll
        for (int m = 0; m < 4; ++m) {
#pragma unroll
            for (int r = 0; r < 4; ++r) {
                const int mm = row0 + wm * 64 + m * 16 + crow + r;
                float v = acc[m][n][r] + bv;
                if (VARIANT == 1) v = fmaxf(v, 0.f);
                Cb[(size_t)mm * Nc + nn] = f2bf(v);
            }
        }
    }
}

// ---------------------------------------------------------------------------
// SPLIT-K K-half GEMM, TLP edition: 128x128 tile, 8 waves (2Mx2Nx2K), BK=64,
// ring-2 (64 KB LDS) + __launch_bounds__(512,4) -> 2 blocks/CU (16 waves):
// the two blocks' barriers interleave asynchronously. blockIdx.z selects a
// K-slice.
//   z=0: Cout = acc + bias + res   (res may alias Cout elementwise)
//   z=1: P1   = acc                (f32 partial; reduced by addp_kernel)
// Body = 97t style: head counted vmcnt(4) + barrier, ds_reads (compiler
// lgkmcnt), 16 MFMA, trailing barrier, tail stage(t+2) (WAR sealed).
// wk=1 partials reduced into wk=0 via 64 KB LDS scratch at end.
// Swizzle: phys slot p of row r holds logical slot p^(r&7); staging
// pre-swizzles the global source column (rule #21 both-sides).
// Requires M%128==0, Nc%128==0, Kslice%64==0, Kslice/64 >= 2, grid%8==0.
// ---------------------------------------------------------------------------
__global__ __launch_bounds__(512, 4) void gemm_kh2_kernel(
    const unsigned short* __restrict__ A,
    const unsigned short* __restrict__ W,
    const float* __restrict__ bias,
    const float* __restrict__ res,
    float* __restrict__ Cout,
    float* __restrict__ P1,
    int Nc, int K, int Kslice) {
    __shared__ unsigned short smem[2][16384];   // 2 x (128+128) rows x 64 x 2B

    const int tid  = threadIdx.x;
    const int lane = tid & 63;
    const int wv   = tid >> 6;
    const int wk   = wv >> 2;          // K-half within BK=64
    const int wm   = (wv >> 1) & 1;    // M-half
    const int wn   = wv & 1;           // N-half

    int bx = blockIdx.x, by = blockIdx.y;
    {   // bijective XCD chunk swizzle (per-slice grid %8 == 0)
        const int gx  = gridDim.x;
        const int nwg = gx * gridDim.y;
        const int lin = by * gx + bx;
        const int sl  = (lin & 7) * (nwg >> 3) + (lin >> 3);
        bx = sl % gx; by = sl / gx;
    }
    const int row0 = by * 128;
    const int col0 = bx * 128;
    const int kbase = blockIdx.z * Kslice;
    const int NT   = Kslice >> 6;

    const int srow = lane >> 3;
    const int sq   = ((lane & 7) ^ ((lane >> 3) & 7)) * 8;   // elems
    const unsigned short* Ag = A + (size_t)(row0 + srow) * K + kbase + sq;
    const unsigned short* Wg = W + (size_t)(col0 + srow) * K + kbase + sq;

    auto stage = [&](int t) {
        unsigned short* dst = &smem[t & 1][0];
#pragma unroll
        for (int s = 0; s < 2; ++s) {
            const int r = (wv + s * 8) * 8;
            __builtin_amdgcn_global_load_lds(
                (const __attribute__((address_space(1))) unsigned int*)(Ag + (size_t)r * K + t * 64),
                (__attribute__((address_space(3))) unsigned int*)(dst + r * 64), 16, 0, 0);
        }
#pragma unroll
        for (int s = 0; s < 2; ++s) {
            const int r = (wv + s * 8) * 8;
            __builtin_amdgcn_global_load_lds(
                (const __attribute__((address_space(1))) unsigned int*)(Wg + (size_t)r * K + t * 64),
                (__attribute__((address_space(3))) unsigned int*)(dst + 8192 + r * 64), 16, 0, 0);
        }
    };

    const int frow = lane & 15;
    const int quad = lane >> 4;
    const int phys = ((wk * 4 + quad) ^ (frow & 7)) * 8;     // elems
    const int abase = (wm * 64 + frow) * 64 + phys;
    const int bbase = 8192 + (wn * 64 + frow) * 64 + phys;

    floatx4 acc[4][4];
#pragma unroll
    for (int m = 0; m < 4; ++m)
#pragma unroll
        for (int n = 0; n < 4; ++n) acc[m][n] = (floatx4){0.f, 0.f, 0.f, 0.f};

    stage(0); stage(1);

    for (int t = 0; t < NT; ++t) {
        if (t == NT - 1) { SWAIT("vmcnt(0)"); } else { SWAIT("vmcnt(4)"); }
        __builtin_amdgcn_s_barrier();
        SCHEDBAR();

        const unsigned short* buf = &smem[t & 1][0];
        bf16x8 af0 = *(const bf16x8*)(buf + abase);
        bf16x8 af1 = *(const bf16x8*)(buf + abase + 1024);
        bf16x8 af2 = *(const bf16x8*)(buf + abase + 2048);
        bf16x8 af3 = *(const bf16x8*)(buf + abase + 3072);
        bf16x8 bf0 = *(const bf16x8*)(buf + bbase);
        bf16x8 bf1 = *(const bf16x8*)(buf + bbase + 1024);
        bf16x8 bf2 = *(const bf16x8*)(buf + bbase + 2048);
        bf16x8 bf3 = *(const bf16x8*)(buf + bbase + 3072);

        __builtin_amdgcn_s_setprio(1);
#pragma unroll
        for (int m = 0; m < 4; ++m)
            acc[m][0] = __builtin_amdgcn_mfma_f32_16x16x32_bf16(
                (m == 0 ? af0 : m == 1 ? af1 : m == 2 ? af2 : af3), bf0, acc[m][0], 0, 0, 0);
#pragma unroll
        for (int m = 0; m < 4; ++m)
            acc[m][1] = __builtin_amdgcn_mfma_f32_16x16x32_bf16(
                (m == 0 ? af0 : m == 1 ? af1 : m == 2 ? af2 : af3), bf1, acc[m][1], 0, 0, 0);
#pragma unroll
        for (int m = 0; m < 4; ++m)
            acc[m][2] = __builtin_amdgcn_mfma_f32_16x16x32_bf16(
                (m == 0 ? af0 : m == 1 ? af1 : m == 2 ? af2 : af3), bf2, acc[m][2], 0, 0, 0);
#pragma unroll
        for (int m = 0; m < 4; ++m)
            acc[m][3] = __builtin_amdgcn_mfma_f32_16x16x32_bf16(
                (m == 0 ? af0 : m == 1 ? af1 : m == 2 ? af2 : af3), bf3, acc[m][3], 0, 0, 0);
        __builtin_amdgcn_s_setprio(0);
        SCHEDBAR();
        __builtin_amdgcn_s_barrier();
        SCHEDBAR();
        if (t + 2 < NT) stage(t + 2);
        SCHEDBAR();
    }

    // cross-wk reduction: wk=1 partials -> LDS (64 KB scratch) -> wk=0 adds
    __syncthreads();
    float* pbuf = (float*)&smem[0][0];
    const int pair = wm * 2 + wn;
    if (wk == 1) {
#pragma unroll
        for (int m = 0; m < 4; ++m)
#pragma unroll
            for (int n = 0; n < 4; ++n)
                *(floatx4*)&pbuf[pair * 4096 + (m * 4 + n) * 256 + lane * 4] = acc[m][n];
    }
    __syncthreads();
    if (wk == 0) {
        const int crow = (lane >> 4) * 4;
        const int ccol = lane & 15;
        const bool final_z = (blockIdx.z == 0);
#pragma unroll
        for (int n = 0; n < 4; ++n) {
            const int nn = col0 + wn * 64 + n * 16 + ccol;
            const float bv = final_z ? bias[nn] : 0.f;
#pragma unroll
            for (int m = 0; m < 4; ++m) {
                floatx4 p = *(const floatx4*)&pbuf[pair * 4096 + (m * 4 + n) * 256 + lane * 4];
#pragma unroll
                for (int r = 0; r < 4; ++r) {
                    const int mm = row0 + wm * 64 + m * 16 + crow + r;
                    const float v = acc[m][n][r] + p[r];
                    if (final_z) {
                        Cout[(size_t)mm * Nc + nn] = v + bv + res[(size_t)mm * Nc + nn];
                    } else {
                        P1[(size_t)mm * Nc + nn] = v;
                    }
                }
            }
        }
    }
}

// ---------------------------------------------------------------------------
// K-half GEMM (ring-4, 1 block/CU) — retained for out-proj (K=1024).
// Output: f32 = acc + bias + res (res may alias Cout elementwise).
// ---------------------------------------------------------------------------
__global__ __launch_bounds__(512, 2) void gemm_kh_kernel(
    const unsigned short* __restrict__ A,
    const unsigned short* __restrict__ W,
    const float* __restrict__ bias,
    const float* res, float* Cout, int Nc, int K) {
    __shared__ unsigned short smem[4][16384];

    const int tid  = threadIdx.x;
    const int lane = tid & 63;
    const int wv   = tid >> 6;
    const int wk   = wv >> 2;
    const int wm   = (wv >> 1) & 1;
    const int wn   = wv & 1;

    int bx = blockIdx.x, by = blockIdx.y;
    {
        const int gx  = gridDim.x;
        const int nwg = gx * gridDim.y;
        const int lin = by * gx + bx;
        const int sl  = (lin & 7) * (nwg >> 3) + (lin >> 3);
        bx = sl % gx; by = sl / gx;
    }
    const int row0 = by * 128;
    const int col0 = bx * 128;
    const int NT   = K >> 6;

    const int srow = lane >> 3;
    const int sq   = ((lane & 7) ^ ((lane >> 3) & 7)) * 8;
    const unsigned short* Ag = A + (size_t)(row0 + srow) * K + sq;
    const unsigned short* Wg = W + (size_t)(col0 + srow) * K + sq;

    auto stage = [&](int t) {
        unsigned short* dst = &smem[t & 3][0];
#pragma unroll
        for (int s = 0; s < 2; ++s) {
            const int r = (wv + s * 8) * 8;
            __builtin_amdgcn_global_load_lds(
                (const __attribute__((address_space(1))) unsigned int*)(Ag + (size_t)r * K + t * 64),
                (__attribute__((address_space(3))) unsigned int*)(dst + r * 64), 16, 0, 0);
        }
#pragma unroll
        for (int s = 0; s < 2; ++s) {
            const int r = (wv + s * 8) * 8;
            __builtin_amdgcn_global_load_lds(
                (const __attribute__((address_space(1))) unsigned int*)(Wg + (size_t)r * K + t * 64),
                (__attribute__((address_space(3))) unsigned int*)(dst + 8192 + r * 64), 16, 0, 0);
        }
    };

    const int frow = lane & 15;
    const int quad = lane >> 4;
    const int phys = ((wk * 4 + quad) ^ (frow & 7)) * 8;
    const int abase = (wm * 64 + frow) * 64 + phys;
    const int bbase = 8192 + (wn * 64 + frow) * 64 + phys;

    floatx4 acc[4][4];
#pragma unroll
    for (int m = 0; m < 4; ++m)
#pragma unroll
        for (int n = 0; n < 4; ++n) acc[m][n] = (floatx4){0.f, 0.f, 0.f, 0.f};

    bf16x8 afA[4], afB[4];

    stage(0); stage(1); stage(2);
    SWAIT("vmcnt(8)");
    __builtin_amdgcn_s_barrier();
    SCHEDBAR();
#pragma unroll
    for (int m = 0; m < 4; ++m)
        afA[m] = *(const bf16x8*)(&smem[0][0] + abase + m * 1024);

#define KH_BODY(T, AFC, AFN, TAIL)                                             \
    {                                                                          \
        const int t_ = (T);                                                    \
        if (!(TAIL)) vm_wait_rt<2>(NT - 2 - t_);                               \
        __builtin_amdgcn_s_barrier();                                          \
        SCHEDBAR();                                                            \
        if (t_ + 3 < NT) stage(t_ + 3);                                        \
        const unsigned short* buf_ = &smem[t_ & 3][0];                         \
        bf16x8 bfr0 = *(const bf16x8*)(buf_ + bbase);                          \
        bf16x8 bfr1 = *(const bf16x8*)(buf_ + bbase + 1024);                   \
        SCHEDBAR();                                                            \
        bf16x8 bfr2 = *(const bf16x8*)(buf_ + bbase + 2048);                   \
        bf16x8 bfr3 = *(const bf16x8*)(buf_ + bbase + 3072);                   \
        if (!(TAIL)) {                                                         \
            const unsigned short* nbuf_ = &smem[(t_ + 1) & 3][0];              \
            _Pragma("unroll")                                                  \
            for (int m = 0; m < 4; ++m)                                        \
                AFN[m] = *(const bf16x8*)(nbuf_ + abase + m * 1024);           \
        }                                                                      \
        SCHEDBAR();                                                            \
        if (TAIL) { SWAIT("lgkmcnt(2)"); } else { SWAIT("lgkmcnt(6)"); }       \
        SCHEDBAR();                                                            \
        __builtin_amdgcn_s_setprio(1);                                         \
        _Pragma("unroll")                                                      \
        for (int m = 0; m < 4; ++m) {                                          \
            acc[m][0] = __builtin_amdgcn_mfma_f32_16x16x32_bf16(               \
                AFC[m], bfr0, acc[m][0], 0, 0, 0);                             \
            acc[m][1] = __builtin_amdgcn_mfma_f32_16x16x32_bf16(               \
                AFC[m], bfr1, acc[m][1], 0, 0, 0);                             \
        }                                                                      \
        SCHEDBAR();                                                            \
        if (TAIL) { SWAIT("lgkmcnt(0)"); } else { SWAIT("lgkmcnt(4)"); }       \
        SCHEDBAR();                                                            \
        _Pragma("unroll")                                                      \
        for (int m = 0; m < 4; ++m) {                                          \
            acc[m][2] = __builtin_amdgcn_mfma_f32_16x16x32_bf16(               \
                AFC[m], bfr2, acc[m][2], 0, 0, 0);                             \
            acc[m][3] = __builtin_amdgcn_mfma_f32_16x16x32_bf16(               \
                AFC[m], bfr3, acc[m][3], 0, 0, 0);                             \
        }                                                                      \
        __builtin_amdgcn_s_setprio(0);                                         \
        SCHEDBAR();                                                            \
    }

    int t = 0;
    for (; t < NT - 2; t += 2) {
        KH_BODY(t,     afA, afB, false);
        KH_BODY(t + 1, afB, afA, false);
    }
    KH_BODY(NT - 2, afA, afB, false);
    KH_BODY(NT - 1, afB, afA, true);
#undef KH_BODY

    __syncthreads();
    float* pbuf = (float*)&smem[0][0];
    const int pair = wm * 2 + wn;
    if (wk == 1) {
#pragma unroll
        for (int m = 0; m < 4; ++m)
#pragma unroll
            for (int n = 0; n < 4; ++n)
                *(floatx4*)&pbuf[pair * 4096 + (m * 4 + n) * 256 + lane * 4] = acc[m][n];
    }
    __syncthreads();
    if (wk == 0) {
        const int crow = (lane >> 4) * 4;
        const int ccol = lane & 15;
#pragma unroll
        for (int n = 0; n < 4; ++n) {
            const int nn = col0 + wn * 64 + n * 16 + ccol;
            const float bv = bias[nn];
#pragma unroll
            for (int m = 0; m < 4; ++m) {
                floatx4 p = *(const floatx4*)&pbuf[pair * 4096 + (m * 4 + n) * 256 + lane * 4];
#pragma unroll
                for (int r = 0; r < 4; ++r) {
                    const int mm = row0 + wm * 64 + m * 16 + crow + r;
                    Cout[(size_t)mm * Nc + nn] =
                        acc[m][n][r] + p[r] + bv + res[(size_t)mm * Nc + nn];
                }
            }
        }
    }
}

// ---------------------------------------------------------------------------
// Flash-style MFMA attention (unchanged). rel_bias finite only for
// 0 <= i-j < 512. One block = 64 Q rows for (b,h); 4 waves; online softmax.
// ---------------------------------------------------------------------------
__global__ __launch_bounds__(256) void attn_mfma_kernel(
    const unsigned short* __restrict__ qkv,
    const float* __restrict__ rel_pos,
    unsigned short* __restrict__ o) {
    __shared__ unsigned short K_s[2][64][32];     // 8 KB
    __shared__ unsigned short V_s[64][72];        // 9 KB  [d][key]
    __shared__ unsigned short P_s[4][2][16][32];  // 8 KB  per-wave
    __shared__ float rel_s[MAXLEN];               // 2 KB

    const int qt = blockIdx.x, h = blockIdx.y, b = blockIdx.z;
    const int q0 = qt * 64;
    const int tid  = threadIdx.x;
    const int lane = tid & 63;
    const int w    = tid >> 6;
    const int quad = lane >> 4;
    const int c15  = lane & 15;

    rel_s[tid]       = rel_pos[h * MAXLEN + tid];
    rel_s[tid + 256] = rel_pos[h * MAXLEN + tid + 256];

    const size_t rowstride = 3 * EE;
    const size_t base_q = (size_t)(b * NN) * rowstride + h * DD;
    const size_t base_k = base_q + EE;
    const size_t base_v = base_q + 2 * EE;

    bf16x8 aq[2];
    {
        const unsigned short* qrow =
            qkv + base_q + (size_t)(q0 + w * 16 + c15) * rowstride + quad * 8;
        aq[0] = *(const bf16x8*)(qrow);
        aq[1] = *(const bf16x8*)(qrow + 32);
    }

    floatx4 Oacc[4];
#pragma unroll
    for (int j = 0; j < 4; ++j) Oacc[j] = (floatx4){0.f, 0.f, 0.f, 0.f};
    float m_r[4], l_r[4];
#pragma unroll
    for (int r = 0; r < 4; ++r) { m_r[r] = -1e30f; l_r[r] = 0.f; }

    const int jlo = max(0, q0 - (MAXLEN - 1));
    const int c0 = jlo >> 6;
    const int c1 = (q0 + 63) >> 6;

    for (int cc = c0; cc <= c1; ++cc) {
        const int jb0 = cc << 6;
        __syncthreads();

        {
            const int krow = w * 16 + (lane >> 2);
            const int dofs = (lane & 3) * 8;
            const unsigned short* gk =
                qkv + base_k + (size_t)(jb0 + krow) * rowstride + dofs;
            __builtin_amdgcn_global_load_lds(
                (const __attribute__((address_space(1))) unsigned int*)gk,
                (__attribute__((address_space(3))) unsigned int*)&K_s[0][w * 16][0],
                16, 0, 0);
            __builtin_amdgcn_global_load_lds(
                (const __attribute__((address_space(1))) unsigned int*)(gk + 32),
                (__attribute__((address_space(3))) unsigned int*)&K_s[1][w * 16][0],
                16, 0, 0);
        }
        {
            const int key = lane;
            const int d0  = w * 16;
            const unsigned short* gv =
                qkv + base_v + (size_t)(jb0 + key) * rowstride + d0;
            ushort8 va = *(const ushort8*)(gv);
            ushort8 vb = *(const ushort8*)(gv + 8);
#pragma unroll
            for (int ii = 0; ii < 8; ++ii) V_s[d0 + ii][key] = va[ii];
#pragma unroll
            for (int ii = 0; ii < 8; ++ii) V_s[d0 + 8 + ii][key] = vb[ii];
        }
        __syncthreads();

        floatx4 S[4];
#pragma unroll
        for (int jb = 0; jb < 4; ++jb) {
            S[jb] = (floatx4){0.f, 0.f, 0.f, 0.f};
            bf16x8 bk0 = *(const bf16x8*)&K_s[0][jb * 16 + c15][quad * 8];
            bf16x8 bk1 = *(const bf16x8*)&K_s[1][jb * 16 + c15][quad * 8];
            S[jb] = __builtin_amdgcn_mfma_f32_16x16x32_bf16(aq[0], bk0, S[jb], 0, 0, 0);
            S[jb] = __builtin_amdgcn_mfma_f32_16x16x32_bf16(aq[1], bk1, S[jb], 0, 0, 0);
        }

        const int i_base = q0 + w * 16 + quad * 4;
        float sv[4][4];
        float mc[4] = {-1e30f, -1e30f, -1e30f, -1e30f};
#pragma unroll
        for (int jb = 0; jb < 4; ++jb) {
            const int jg = jb0 + jb * 16 + c15;
#pragma unroll
            for (int r = 0; r < 4; ++r) {
                const int rel = (i_base + r) - jg;
                float s;
                if (rel >= 0 && rel < MAXLEN) s = S[jb][r] * 0.125f + rel_s[rel];
                else                          s = -1e30f;
                sv[jb][r] = s;
                mc[r] = fmaxf(mc[r], s);
            }
        }
#pragma unroll
        for (int off = 1; off < 16; off <<= 1)
#pragma unroll
            for (int r = 0; r < 4; ++r) mc[r] = fmaxf(mc[r], __shfl_xor(mc[r], off));

        float alpha[4], psum[4];
#pragma unroll
        for (int r = 0; r < 4; ++r) {
            const float mn = fmaxf(m_r[r], mc[r]);
            alpha[r] = __expf(m_r[r] - mn);
            m_r[r] = mn;
            psum[r] = 0.f;
        }
#pragma unroll
        for (int jb = 0; jb < 4; ++jb)
#pragma unroll
            for (int r = 0; r < 4; ++r) {
                const float p = __expf(sv[jb][r] - m_r[r]);
                sv[jb][r] = p;
                psum[r] += p;
            }
#pragma unroll
        for (int off = 1; off < 16; off <<= 1)
#pragma unroll
            for (int r = 0; r < 4; ++r) psum[r] += __shfl_xor(psum[r], off);
#pragma unroll
        for (int r = 0; r < 4; ++r) l_r[r] = l_r[r] * alpha[r] + psum[r];
#pragma unroll
        for (int jb = 0; jb < 4; ++jb)
#pragma unroll
            for (int r = 0; r < 4; ++r) Oacc[jb][r] *= alpha[r];

#pragma unroll
        for (int jb = 0; jb < 4; ++jb)
#pragma unroll
            for (int r = 0; r < 4; ++r)
                P_s[w][jb >> 1][quad * 4 + r][(jb & 1) * 16 + c15] = f2bf(sv[jb][r]);

        bf16x8 ap0 = *(const bf16x8*)&P_s[w][0][c15][quad * 8];
        bf16x8 ap1 = *(const bf16x8*)&P_s[w][1][c15][quad * 8];

#pragma unroll
        for (int jd = 0; jd < 4; ++jd) {
            bf16x8 bv0 = *(const bf16x8*)&V_s[jd * 16 + c15][quad * 8];
            bf16x8 bv1 = *(const bf16x8*)&V_s[jd * 16 + c15][32 + quad * 8];
            Oacc[jd] = __builtin_amdgcn_mfma_f32_16x16x32_bf16(ap0, bv0, Oacc[jd], 0, 0, 0);
            Oacc[jd] = __builtin_amdgcn_mfma_f32_16x16x32_bf16(ap1, bv1, Oacc[jd], 0, 0, 0);
        }
    }

    float inv[4];
#pragma unroll
    for (int r = 0; r < 4; ++r) inv[r] = 1.0f / l_r[r];
#pragma unroll
    for (int jd = 0; jd < 4; ++jd) {
#pragma unroll
        for (int r = 0; r < 4; ++r) {
            const int row = q0 + w * 16 + quad * 4 + r;
            const int col = h * DD + jd * 16 + c15;
            o[(size_t)(b * NN + row) * EE + col] = f2bf(Oacc[jd][r] * inv[r]);
        }
    }
}

// ---------------------------------------------------------------------------
// Launch
// ---------------------------------------------------------------------------
extern "C" void kernel_launch(void* const* d_in, const int* in_sizes, int n_in,
                              void* d_out, int out_size, void* d_ws, size_t ws_size,
                              hipStream_t stream) {
    const float* x         = (const float*)d_in[0];
    const float* rel_pos   = (const float*)d_in[1];
    const float* in_proj_w = (const float*)d_in[2];
    const float* in_proj_b = (const float*)d_in[3];
    const float* out_w     = (const float*)d_in[4];
    const float* out_b     = (const float*)d_in[5];
    const float* w1        = (const float*)d_in[6];
    const float* b1        = (const float*)d_in[7];
    const float* w2        = (const float*)d_in[8];
    const float* b2        = (const float*)d_in[9];
    const float* ln1_g     = (const float*)d_in[10];
    const float* ln1_b     = (const float*)d_in[11];
    const float* ln2_g     = (const float*)d_in[12];
    const float* ln2_b     = (const float*)d_in[13];
    float* out = (float*)d_out;

    char* wsb = (char*)d_ws;
    const size_t MB = 1024 * 1024;
    unsigned short* wqkv_b = (unsigned short*)(wsb + 0);        // 6 MB
    unsigned short* wout_b = (unsigned short*)(wsb + 6 * MB);   // 2 MB
    unsigned short* w1_b   = (unsigned short*)(wsb + 8 * MB);   // 8 MB
    unsigned short* w2_b   = (unsigned short*)(wsb + 16 * MB);  // 8 MB
    unsigned short* xn_b   = (unsigned short*)(wsb + 24 * MB);  // 8 MB (xn, then xm)
    unsigned short* qkv_b  = (unsigned short*)(wsb + 32 * MB);  // 24 MB
    unsigned short* h_b    = (unsigned short*)(wsb + 32 * MB);  // 32 MB (reuses qkv+o)
    unsigned short* o_b    = (unsigned short*)(wsb + 56 * MB);  // 8 MB
    // FFN2 split-K partial: 16 MB f32 over [0,16MB) — wqkv/wout/w1 are all
    // dead by FFN2 time (QKV, out-proj, FFN1 already done); rewritten fresh
    // by f2bf_all at the start of every launch (graph-replay safe).
    float* p1 = (float*)(wsb + 0);

    const int Mrows = BB * NN;   // 4096

    // all four weight conversions in one launch (3145728 float4s)
    f2bf_all_kernel<<<3 * EE * EE / 256, 256, 0, stream>>>(
        in_proj_w, out_w, w1, w2, wqkv_b, wout_b, w1_b, w2_b);

    ln_kernel<<<Mrows, 256, 0, stream>>>(x, ln1_g, ln1_b, xn_b);
    // QKV: 128^2 TLP kernel, grid 24x32 = 768 blocks (3/CU, 12 waves/CU)
    gemm97t_kernel<0><<<dim3(3 * EE / 128, Mrows / 128), 256, 0, stream>>>(
        xn_b, wqkv_b, in_proj_b, qkv_b, 3 * EE, EE);
    attn_mfma_kernel<<<dim3(NN / 64, HH, BB), 256, 0, stream>>>(qkv_b, rel_pos, o_b);
    // out-proj + residual: K-half kernel (grid-capped 8x32 = 256 blocks)
    gemm_kh_kernel<<<dim3(EE / 128, Mrows / 128), 512, 0, stream>>>(
        o_b, wout_b, out_b, x, out, EE, EE);
    ln_kernel<<<Mrows, 256, 0, stream>>>(out, ln2_g, ln2_b, xn_b);
    // FFN1: 128^2 TLP kernel, grid 32x32 = 1024 blocks (3/CU resident), relu
    gemm97t_kernel<1><<<dim3(4 * EE / 128, Mrows / 128), 256, 0, stream>>>(
        xn_b, w1_b, b1, h_b, 4 * EE, EE);
    // FFN2 split-K=2: grid 8x32x2 = 512 blocks (2 blocks/CU, 16 waves/CU).
    // z=0 -> out = acc + b2 + out(in-place res); z=1 -> p1 = acc.
    gemm_kh2_kernel<<<dim3(EE / 128, Mrows / 128, 2), 512, 0, stream>>>(
        h_b, w2_b, b2, out, out, p1, EE, 4 * EE, 2 * EE);
    // reduce: out += p1 (4M floats)
    addp_kernel<<<Mrows * EE / 1024, 256, 0, stream>>>(out, p1);
}

// Round 9
// 341.600 us; speedup vs baseline: 1.0056x; 1.0056x over previous
//
#include <hip/hip_runtime.h>
#include <math.h>

// Problem constants (from reference)
#define BB 4
#define NN 1024
#define EE 1024
#define HH 16
#define DD 64
#define MAXLEN 512
#define EPS 1e-5f

typedef __attribute__((ext_vector_type(8))) __bf16 bf16x8;
typedef __attribute__((ext_vector_type(4))) float floatx4;
typedef __attribute__((ext_vector_type(8))) unsigned short ushort8;

#define SWAIT(s) asm volatile("s_waitcnt " s ::: "memory")
#define SCHEDBAR() __builtin_amdgcn_sched_barrier(0)

__device__ __forceinline__ unsigned short f2bf(float f) {
    unsigned u = __float_as_uint(f);
    u += 0x7fffu + ((u >> 16) & 1u);   // RNE
    return (unsigned short)(u >> 16);
}

// counted vmcnt wait: rem = number of 4-load tile-groups allowed to remain.
template <int MAXR>
__device__ __forceinline__ void vm_wait_rt(int rem) {
    if (rem >= MAXR) {
        if constexpr (MAXR <= 0)      SWAIT("vmcnt(0)");
        else if constexpr (MAXR == 1) SWAIT("vmcnt(4)");
        else if constexpr (MAXR == 2) SWAIT("vmcnt(8)");
        else                          SWAIT("vmcnt(12)");
        return;
    }
    if (rem <= 0) { SWAIT("vmcnt(0)"); return; }
    if (rem == 1) { SWAIT("vmcnt(4)"); return; }
    if constexpr (MAXR >= 3) { if (rem == 2) { SWAIT("vmcnt(8)");  return; } }
}

// ---------------------------------------------------------------------------
// fp32 -> bf16 for all four weight matrices in ONE launch (4 segments).
// ---------------------------------------------------------------------------
__global__ __launch_bounds__(256) void f2bf_all_kernel(
    const float* __restrict__ s0, const float* __restrict__ s1,
    const float* __restrict__ s2, const float* __restrict__ s3,
    unsigned short* __restrict__ d0, unsigned short* __restrict__ d1,
    unsigned short* __restrict__ d2, unsigned short* __restrict__ d3) {
    const int C0 = 3 * EE * EE / 4;            // 786432
    const int C1 = C0 + EE * EE / 4;           // 1048576
    const int C2 = C1 + EE * EE;               // 2097152
    int i = blockIdx.x * 256 + threadIdx.x;
    const float* in; unsigned short* out; int j;
    if (i < C0)      { in = s0; out = d0; j = i; }
    else if (i < C1) { in = s1; out = d1; j = i - C0; }
    else if (i < C2) { in = s2; out = d2; j = i - C1; }
    else             { in = s3; out = d3; j = i - C2; }
    float4 v = ((const float4*)in)[j];
    ushort4 o;
    o.x = f2bf(v.x); o.y = f2bf(v.y); o.z = f2bf(v.z); o.w = f2bf(v.w);
    ((ushort4*)out)[j] = o;
}

// ---------------------------------------------------------------------------
// LayerNorm: one block per row of E=1024; float4 loads; bf16 ushort4 output.
// ---------------------------------------------------------------------------
__global__ __launch_bounds__(256) void ln_kernel(const float* __restrict__ x,
                                                 const float* __restrict__ g,
                                                 const float* __restrict__ b,
                                                 unsigned short* __restrict__ out) {
    const int row = blockIdx.x;
    const int tid = threadIdx.x;
    const float4 v = ((const float4*)(x + (size_t)row * EE))[tid];
    float s  = v.x + v.y + v.z + v.w;
    float s2 = v.x * v.x + v.y * v.y + v.z * v.z + v.w * v.w;
    for (int off = 32; off > 0; off >>= 1) {
        s  += __shfl_xor(s, off);
        s2 += __shfl_xor(s2, off);
    }
    __shared__ float red[8];
    const int wave = tid >> 6, lane = tid & 63;
    if (lane == 0) { red[wave] = s; red[4 + wave] = s2; }
    __syncthreads();
    s  = red[0] + red[1] + red[2] + red[3];
    s2 = red[4] + red[5] + red[6] + red[7];
    const float mu  = s * (1.0f / EE);
    const float var = s2 * (1.0f / EE) - mu * mu;
    const float inv = rsqrtf(var + EPS);
    const float4 gv = ((const float4*)g)[tid];
    const float4 bv = ((const float4*)b)[tid];
    ushort4 o;
    o.x = f2bf((v.x - mu) * inv * gv.x + bv.x);
    o.y = f2bf((v.y - mu) * inv * gv.y + bv.y);
    o.z = f2bf((v.z - mu) * inv * gv.z + bv.z);
    o.w = f2bf((v.w - mu) * inv * gv.w + bv.w);
    ((ushort4*)(out + (size_t)row * EE))[tid] = o;
}

// ---------------------------------------------------------------------------
// m97-style TLP GEMM: 128x128 tile, 4 waves (64x64 each), ring-2 BK=32
// buffers (32 KB LDS) -> 3 blocks/CU (12 waves). Counted vmcnt(4); tile t+2
// staged at the TAIL of body t (trailing barrier seals WAR). Compiler manages
// lgkmcnt. Both-sides swizzle. XCD chunk swizzle (grid %8 == 0).
// VARIANT: 0 = bias + bf16 out; 1 = bias + relu + bf16 out.
// ---------------------------------------------------------------------------
template <int VARIANT>
__global__ __launch_bounds__(256, 3) void gemm97t_kernel(
    const unsigned short* __restrict__ A,
    const unsigned short* __restrict__ W,
    const float* __restrict__ bias,
    void* __restrict__ Cout, int Nc, int K) {
    __shared__ unsigned short smem[2][8192];

    const int tid  = threadIdx.x;
    const int lane = tid & 63;
    const int wv   = tid >> 6;          // 0..3
    const int wm   = wv >> 1;
    const int wn   = wv & 1;

    int bx = blockIdx.x, by = blockIdx.y;
    {   // bijective XCD chunk swizzle (grid %8 == 0)
        const int gx  = gridDim.x;
        const int nwg = gx * gridDim.y;
        const int lin = by * gx + bx;
        const int sl  = (lin & 7) * (nwg >> 3) + (lin >> 3);
        bx = sl % gx; by = sl / gx;
    }
    const int row0 = by * 128;
    const int col0 = bx * 128;
    const int NT   = K >> 5;

    const int srow = lane >> 2;
    const int sq   = ((lane & 3) ^ ((lane >> 3) & 3)) * 8;   // elems
    const unsigned short* Ag = A + (size_t)(row0 + srow) * K + sq;
    const unsigned short* Wg = W + (size_t)(col0 + srow) * K + sq;

    auto stage = [&](int t) {
        unsigned short* dst = &smem[t & 1][0];
#pragma unroll
        for (int s = 0; s < 2; ++s) {
            const int r = (wv + s * 4) * 16;
            __builtin_amdgcn_global_load_lds(
                (const __attribute__((address_space(1))) unsigned int*)(Ag + (size_t)r * K + t * 32),
                (__attribute__((address_space(3))) unsigned int*)(dst + r * 32), 16, 0, 0);
        }
#pragma unroll
        for (int s = 0; s < 2; ++s) {
            const int r = (wv + s * 4) * 16;
            __builtin_amdgcn_global_load_lds(
                (const __attribute__((address_space(1))) unsigned int*)(Wg + (size_t)r * K + t * 32),
                (__attribute__((address_space(3))) unsigned int*)(dst + 4096 + r * 32), 16, 0, 0);
        }
    };

    const int frow = lane & 15;
    const int quad = lane >> 4;
    const int rq   = (quad ^ ((frow >> 1) & 3)) * 8;
    const int abase = (wm * 64 + frow) * 32 + rq;
    const int bbase = 4096 + (wn * 64 + frow) * 32 + rq;

    floatx4 acc[4][4];
#pragma unroll
    for (int m = 0; m < 4; ++m)
#pragma unroll
        for (int n = 0; n < 4; ++n) acc[m][n] = (floatx4){0.f, 0.f, 0.f, 0.f};

    stage(0); stage(1);

    for (int t = 0; t < NT; ++t) {
        if (t == NT - 1) { SWAIT("vmcnt(0)"); } else { SWAIT("vmcnt(4)"); }
        __builtin_amdgcn_s_barrier();
        SCHEDBAR();

        const unsigned short* buf = &smem[t & 1][0];
        bf16x8 af0 = *(const bf16x8*)(buf + abase);
        bf16x8 af1 = *(const bf16x8*)(buf + abase + 512);
        bf16x8 af2 = *(const bf16x8*)(buf + abase + 1024);
        bf16x8 af3 = *(const bf16x8*)(buf + abase + 1536);
        bf16x8 bf0 = *(const bf16x8*)(buf + bbase);
        bf16x8 bf1 = *(const bf16x8*)(buf + bbase + 512);
        bf16x8 bf2 = *(const bf16x8*)(buf + bbase + 1024);
        bf16x8 bf3 = *(const bf16x8*)(buf + bbase + 1536);

        __builtin_amdgcn_s_setprio(1);
#pragma unroll
        for (int m = 0; m < 4; ++m)
            acc[m][0] = __builtin_amdgcn_mfma_f32_16x16x32_bf16(
                (m == 0 ? af0 : m == 1 ? af1 : m == 2 ? af2 : af3), bf0, acc[m][0], 0, 0, 0);
#pragma unroll
        for (int m = 0; m < 4; ++m)
            acc[m][1] = __builtin_amdgcn_mfma_f32_16x16x32_bf16(
                (m == 0 ? af0 : m == 1 ? af1 : m == 2 ? af2 : af3), bf1, acc[m][1], 0, 0, 0);
#pragma unroll
        for (int m = 0; m < 4; ++m)
            acc[m][2] = __builtin_amdgcn_mfma_f32_16x16x32_bf16(
                (m == 0 ? af0 : m == 1 ? af1 : m == 2 ? af2 : af3), bf2, acc[m][2], 0, 0, 0);
#pragma unroll
        for (int m = 0; m < 4; ++m)
            acc[m][3] = __builtin_amdgcn_mfma_f32_16x16x32_bf16(
                (m == 0 ? af0 : m == 1 ? af1 : m == 2 ? af2 : af3), bf3, acc[m][3], 0, 0, 0);
        __builtin_amdgcn_s_setprio(0);
        SCHEDBAR();
        __builtin_amdgcn_s_barrier();
        SCHEDBAR();
        if (t + 2 < NT) stage(t + 2);
        SCHEDBAR();
    }

    unsigned short* Cb = (unsigned short*)Cout;
    const int crow = (lane >> 4) * 4;
    const int ccol = lane & 15;
#pragma unroll
    for (int n = 0; n < 4; ++n) {
        const int nn = col0 + wn * 64 + n * 16 + ccol;
        const float bv = bias[nn];
#pragma unroll
        for (int m = 0; m < 4; ++m) {
#pragma unroll
            for (int r = 0; r < 4; ++r) {
                const int mm = row0 + wm * 64 + m * 16 + crow + r;
                float v = acc[m][n][r] + bv;
                if (VARIANT == 1) v = fmaxf(v, 0.f);
                Cb[(size_t)mm * Nc + nn] = f2bf(v);
            }
        }
    }
}

// ---------------------------------------------------------------------------
// K-half GEMM (ring-4, 1 block/CU) — out-proj and FFN2 (grid-capped shapes).
// 8 waves as 2Mx2Nx2K, BK=64; wk=1 partials reduced via LDS at end.
// Output: f32 = acc + bias + res (res may alias Cout elementwise).
// ---------------------------------------------------------------------------
__global__ __launch_bounds__(512, 2) void gemm_kh_kernel(
    const unsigned short* __restrict__ A,
    const unsigned short* __restrict__ W,
    const float* __restrict__ bias,
    const float* res, float* Cout, int Nc, int K) {
    __shared__ unsigned short smem[4][16384];

    const int tid  = threadIdx.x;
    const int lane = tid & 63;
    const int wv   = tid >> 6;
    const int wk   = wv >> 2;
    const int wm   = (wv >> 1) & 1;
    const int wn   = wv & 1;

    int bx = blockIdx.x, by = blockIdx.y;
    {
        const int gx  = gridDim.x;
        const int nwg = gx * gridDim.y;
        const int lin = by * gx + bx;
        const int sl  = (lin & 7) * (nwg >> 3) + (lin >> 3);
        bx = sl % gx; by = sl / gx;
    }
    const int row0 = by * 128;
    const int col0 = bx * 128;
    const int NT   = K >> 6;

    const int srow = lane >> 3;
    const int sq   = ((lane & 7) ^ ((lane >> 3) & 7)) * 8;
    const unsigned short* Ag = A + (size_t)(row0 + srow) * K + sq;
    const unsigned short* Wg = W + (size_t)(col0 + srow) * K + sq;

    auto stage = [&](int t) {
        unsigned short* dst = &smem[t & 3][0];
#pragma unroll
        for (int s = 0; s < 2; ++s) {
            const int r = (wv + s * 8) * 8;
            __builtin_amdgcn_global_load_lds(
                (const __attribute__((address_space(1))) unsigned int*)(Ag + (size_t)r * K + t * 64),
                (__attribute__((address_space(3))) unsigned int*)(dst + r * 64), 16, 0, 0);
        }
#pragma unroll
        for (int s = 0; s < 2; ++s) {
            const int r = (wv + s * 8) * 8;
            __builtin_amdgcn_global_load_lds(
                (const __attribute__((address_space(1))) unsigned int*)(Wg + (size_t)r * K + t * 64),
                (__attribute__((address_space(3))) unsigned int*)(dst + 8192 + r * 64), 16, 0, 0);
        }
    };

    const int frow = lane & 15;
    const int quad = lane >> 4;
    const int phys = ((wk * 4 + quad) ^ (frow & 7)) * 8;
    const int abase = (wm * 64 + frow) * 64 + phys;
    const int bbase = 8192 + (wn * 64 + frow) * 64 + phys;

    floatx4 acc[4][4];
#pragma unroll
    for (int m = 0; m < 4; ++m)
#pragma unroll
        for (int n = 0; n < 4; ++n) acc[m][n] = (floatx4){0.f, 0.f, 0.f, 0.f};

    bf16x8 afA[4], afB[4];

    stage(0); stage(1); stage(2);
    SWAIT("vmcnt(8)");
    __builtin_amdgcn_s_barrier();
    SCHEDBAR();
#pragma unroll
    for (int m = 0; m < 4; ++m)
        afA[m] = *(const bf16x8*)(&smem[0][0] + abase + m * 1024);

#define KH_BODY(T, AFC, AFN, TAIL)                                             \
    {                                                                          \
        const int t_ = (T);                                                    \
        if (!(TAIL)) vm_wait_rt<2>(NT - 2 - t_);                               \
        __builtin_amdgcn_s_barrier();                                          \
        SCHEDBAR();                                                            \
        if (t_ + 3 < NT) stage(t_ + 3);                                        \
        const unsigned short* buf_ = &smem[t_ & 3][0];                         \
        bf16x8 bfr0 = *(const bf16x8*)(buf_ + bbase);                          \
        bf16x8 bfr1 = *(const bf16x8*)(buf_ + bbase + 1024);                   \
        SCHEDBAR();                                                            \
        bf16x8 bfr2 = *(const bf16x8*)(buf_ + bbase + 2048);                   \
        bf16x8 bfr3 = *(const bf16x8*)(buf_ + bbase + 3072);                   \
        if (!(TAIL)) {                                                         \
            const unsigned short* nbuf_ = &smem[(t_ + 1) & 3][0];              \
            _Pragma("unroll")                                                  \
            for (int m = 0; m < 4; ++m)                                        \
                AFN[m] = *(const bf16x8*)(nbuf_ + abase + m * 1024);           \
        }                                                                      \
        SCHEDBAR();                                                            \
        if (TAIL) { SWAIT("lgkmcnt(2)"); } else { SWAIT("lgkmcnt(6)"); }       \
        SCHEDBAR();                                                            \
        __builtin_amdgcn_s_setprio(1);                                         \
        _Pragma("unroll")                                                      \
        for (int m = 0; m < 4; ++m) {                                          \
            acc[m][0] = __builtin_amdgcn_mfma_f32_16x16x32_bf16(               \
                AFC[m], bfr0, acc[m][0], 0, 0, 0);                             \
            acc[m][1] = __builtin_amdgcn_mfma_f32_16x16x32_bf16(               \
                AFC[m], bfr1, acc[m][1], 0, 0, 0);                             \
        }                                                                      \
        SCHEDBAR();                                                            \
        if (TAIL) { SWAIT("lgkmcnt(0)"); } else { SWAIT("lgkmcnt(4)"); }       \
        SCHEDBAR();                                                            \
        _Pragma("unroll")                                                      \
        for (int m = 0; m < 4; ++m) {                                          \
            acc[m][2] = __builtin_amdgcn_mfma_f32_16x16x32_bf16(               \
                AFC[m], bfr2, acc[m][2], 0, 0, 0);                             \
            acc[m][3] = __builtin_amdgcn_mfma_f32_16x16x32_bf16(               \
                AFC[m], bfr3, acc[m][3], 0, 0, 0);                             \
        }                                                                      \
        __builtin_amdgcn_s_setprio(0);                                         \
        SCHEDBAR();                                                            \
    }

    int t = 0;
    for (; t < NT - 2; t += 2) {
        KH_BODY(t,     afA, afB, false);
        KH_BODY(t + 1, afB, afA, false);
    }
    KH_BODY(NT - 2, afA, afB, false);
    KH_BODY(NT - 1, afB, afA, true);
#undef KH_BODY

    __syncthreads();
    float* pbuf = (float*)&smem[0][0];
    const int pair = wm * 2 + wn;
    if (wk == 1) {
#pragma unroll
        for (int m = 0; m < 4; ++m)
#pragma unroll
            for (int n = 0; n < 4; ++n)
                *(floatx4*)&pbuf[pair * 4096 + (m * 4 + n) * 256 + lane * 4] = acc[m][n];
    }
    __syncthreads();
    if (wk == 0) {
        const int crow = (lane >> 4) * 4;
        const int ccol = lane & 15;
#pragma unroll
        for (int n = 0; n < 4; ++n) {
            const int nn = col0 + wn * 64 + n * 16 + ccol;
            const float bv = bias[nn];
#pragma unroll
            for (int m = 0; m < 4; ++m) {
                floatx4 p = *(const floatx4*)&pbuf[pair * 4096 + (m * 4 + n) * 256 + lane * 4];
#pragma unroll
                for (int r = 0; r < 4; ++r) {
                    const int mm = row0 + wm * 64 + m * 16 + crow + r;
                    Cout[(size_t)mm * Nc + nn] =
                        acc[m][n][r] + p[r] + bv + res[(size_t)mm * Nc + nn];
                }
            }
        }
    }
}

// ---------------------------------------------------------------------------
// Flash-style MFMA attention, v2: double-buffered K/V LDS, ONE barrier per
// 64-key chunk, async prefetch (issue next K global_load_lds + V register
// loads at iteration top; write V regs to the other buffer at iteration end).
// Bank fixes (octet rule: each aligned 8-lane group of a ds_read_b128 must
// cover all 8 bank-groups):
//  - K_s: GEMM both-sides swizzle (pre-swizzled gll source col, read slot
//    quad ^ ((row>>1)&3))  [was 4-way/octet]
//  - P_s: pitch 32 -> 40 ushorts (80 B, 16B-aligned; groups 5*row mod 8)
//  - V_s: pitch 72 already conflict-free (9*row mod 8)
// Work imbalance: qt reversed so 9-chunk tiles dispatch first.
// WAR ledger: buffer written at end of iter cc was last read in iter cc-1,
// whose reads drained at the top-of-cc __syncthreads (vmcnt+lgkm drain).
// ---------------------------------------------------------------------------
__global__ __launch_bounds__(256) void attn_mfma_kernel(
    const unsigned short* __restrict__ qkv,
    const float* __restrict__ rel_pos,
    unsigned short* __restrict__ o) {
    __shared__ unsigned short K_s[2][2][64][32];   // [buf][d-half][key][32] 16 KB
    __shared__ unsigned short V_s[2][64][72];      // [buf][d][key]        18.4 KB
    __shared__ unsigned short P_s[4][2][16][40];   // pitch 40             10 KB
    __shared__ float rel_s[MAXLEN];                // 2 KB

    const int qt = (gridDim.x - 1) - blockIdx.x;   // heavy tiles first
    const int h = blockIdx.y, b = blockIdx.z;
    const int q0 = qt * 64;
    const int tid  = threadIdx.x;
    const int lane = tid & 63;
    const int w    = tid >> 6;
    const int quad = lane >> 4;
    const int c15  = lane & 15;

    rel_s[tid]       = rel_pos[h * MAXLEN + tid];
    rel_s[tid + 256] = rel_pos[h * MAXLEN + tid + 256];

    const size_t rowstride = 3 * EE;
    const size_t base_q = (size_t)(b * NN) * rowstride + h * DD;
    const size_t base_k = base_q + EE;
    const size_t base_v = base_q + 2 * EE;

    bf16x8 aq[2];
    {
        const unsigned short* qrow =
            qkv + base_q + (size_t)(q0 + w * 16 + c15) * rowstride + quad * 8;
        aq[0] = *(const bf16x8*)(qrow);
        aq[1] = *(const bf16x8*)(qrow + 32);
    }

    // K staging: lane covers key-row (lane>>2), phys slot (lane&3); source
    // col pre-swizzled so reads can XOR the same pattern (GEMM-proven).
    const int krow = w * 16 + (lane >> 2);
    const int kswz = ((lane & 3) ^ ((lane >> 3) & 3)) * 8;   // elems
    auto stageK = [&](int jb0, int buf) {
        const unsigned short* gk =
            qkv + base_k + (size_t)(jb0 + krow) * rowstride + kswz;
        __builtin_amdgcn_global_load_lds(
            (const __attribute__((address_space(1))) unsigned int*)gk,
            (__attribute__((address_space(3))) unsigned int*)&K_s[buf][0][w * 16][0],
            16, 0, 0);
        __builtin_amdgcn_global_load_lds(
            (const __attribute__((address_space(1))) unsigned int*)(gk + 32),
            (__attribute__((address_space(3))) unsigned int*)&K_s[buf][1][w * 16][0],
            16, 0, 0);
    };

    ushort8 va, vb;
    auto loadV = [&](int jb0) {
        const unsigned short* gv =
            qkv + base_v + (size_t)(jb0 + lane) * rowstride + w * 16;
        va = *(const ushort8*)(gv);
        vb = *(const ushort8*)(gv + 8);
    };
    auto writeV = [&](int buf) {
        const int d0 = w * 16;
#pragma unroll
        for (int ii = 0; ii < 8; ++ii) V_s[buf][d0 + ii][lane] = va[ii];
#pragma unroll
        for (int ii = 0; ii < 8; ++ii) V_s[buf][d0 + 8 + ii][lane] = vb[ii];
    };

    floatx4 Oacc[4];
#pragma unroll
    for (int j = 0; j < 4; ++j) Oacc[j] = (floatx4){0.f, 0.f, 0.f, 0.f};
    float m_r[4], l_r[4];
#pragma unroll
    for (int r = 0; r < 4; ++r) { m_r[r] = -1e30f; l_r[r] = 0.f; }

    const int jlo = max(0, q0 - (MAXLEN - 1));
    const int c0 = jlo >> 6;
    const int c1 = (q0 + 63) >> 6;

    // prologue: stage chunk c0 into buffer 0
    stageK(c0 << 6, 0);
    loadV(c0 << 6);
    writeV(0);                 // compiler inserts vmcnt wait for va/vb

    for (int cc = c0; cc <= c1; ++cc) {
        const int jb0 = cc << 6;
        const int buf = (cc - c0) & 1;
        __syncthreads();       // drains vm+lgkm: K_s/V_s[buf] resident

        if (cc < c1) {         // issue next chunk's loads early (latency cover)
            loadV((cc + 1) << 6);
            stageK((cc + 1) << 6, buf ^ 1);
        }

        floatx4 S[4];
#pragma unroll
        for (int jb = 0; jb < 4; ++jb) {
            S[jb] = (floatx4){0.f, 0.f, 0.f, 0.f};
            const int rsw = (quad ^ (((jb * 16 + c15) >> 1) & 3)) * 8;
            bf16x8 bk0 = *(const bf16x8*)&K_s[buf][0][jb * 16 + c15][rsw];
            bf16x8 bk1 = *(const bf16x8*)&K_s[buf][1][jb * 16 + c15][rsw];
            S[jb] = __builtin_amdgcn_mfma_f32_16x16x32_bf16(aq[0], bk0, S[jb], 0, 0, 0);
            S[jb] = __builtin_amdgcn_mfma_f32_16x16x32_bf16(aq[1], bk1, S[jb], 0, 0, 0);
        }

        const int i_base = q0 + w * 16 + quad * 4;
        float sv[4][4];
        float mc[4] = {-1e30f, -1e30f, -1e30f, -1e30f};
#pragma unroll
        for (int jb = 0; jb < 4; ++jb) {
            const int jg = jb0 + jb * 16 + c15;
#pragma unroll
            for (int r = 0; r < 4; ++r) {
                const int rel = (i_base + r) - jg;
                float s;
                if (rel >= 0 && rel < MAXLEN) s = S[jb][r] * 0.125f + rel_s[rel];
                else                          s = -1e30f;
                sv[jb][r] = s;
                mc[r] = fmaxf(mc[r], s);
            }
        }
#pragma unroll
        for (int off = 1; off < 16; off <<= 1)
#pragma unroll
            for (int r = 0; r < 4; ++r) mc[r] = fmaxf(mc[r], __shfl_xor(mc[r], off));

        float alpha[4], psum[4];
#pragma unroll
        for (int r = 0; r < 4; ++r) {
            const float mn = fmaxf(m_r[r], mc[r]);
            alpha[r] = __expf(m_r[r] - mn);
            m_r[r] = mn;
            psum[r] = 0.f;
        }
#pragma unroll
        for (int jb = 0; jb < 4; ++jb)
#pragma unroll
            for (int r = 0; r < 4; ++r) {
                const float p = __expf(sv[jb][r] - m_r[r]);
                sv[jb][r] = p;
                psum[r] += p;
            }
#pragma unroll
        for (int off = 1; off < 16; off <<= 1)
#pragma unroll
            for (int r = 0; r < 4; ++r) psum[r] += __shfl_xor(psum[r], off);
#pragma unroll
        for (int r = 0; r < 4; ++r) l_r[r] = l_r[r] * alpha[r] + psum[r];
#pragma unroll
        for (int jb = 0; jb < 4; ++jb)
#pragma unroll
            for (int r = 0; r < 4; ++r) Oacc[jb][r] *= alpha[r];

#pragma unroll
        for (int jb = 0; jb < 4; ++jb)
#pragma unroll
            for (int r = 0; r < 4; ++r)
                P_s[w][jb >> 1][quad * 4 + r][(jb & 1) * 16 + c15] = f2bf(sv[jb][r]);

        bf16x8 ap0 = *(const bf16x8*)&P_s[w][0][c15][quad * 8];
        bf16x8 ap1 = *(const bf16x8*)&P_s[w][1][c15][quad * 8];

#pragma unroll
        for (int jd = 0; jd < 4; ++jd) {
            bf16x8 bv0 = *(const bf16x8*)&V_s[buf][jd * 16 + c15][quad * 8];
            bf16x8 bv1 = *(const bf16x8*)&V_s[buf][jd * 16 + c15][32 + quad * 8];
            Oacc[jd] = __builtin_amdgcn_mfma_f32_16x16x32_bf16(ap0, bv0, Oacc[jd], 0, 0, 0);
            Oacc[jd] = __builtin_amdgcn_mfma_f32_16x16x32_bf16(ap1, bv1, Oacc[jd], 0, 0, 0);
        }

        if (cc < c1) writeV(buf ^ 1);   // vmcnt wait on va/vb handled by compiler
    }

    float inv[4];
#pragma unroll
    for (int r = 0; r < 4; ++r) inv[r] = 1.0f / l_r[r];
#pragma unroll
    for (int jd = 0; jd < 4; ++jd) {
#pragma unroll
        for (int r = 0; r < 4; ++r) {
            const int row = q0 + w * 16 + quad * 4 + r;
            const int col = h * DD + jd * 16 + c15;
            o[(size_t)(b * NN + row) * EE + col] = f2bf(Oacc[jd][r] * inv[r]);
        }
    }
}

// ---------------------------------------------------------------------------
// Launch
// ---------------------------------------------------------------------------
extern "C" void kernel_launch(void* const* d_in, const int* in_sizes, int n_in,
                              void* d_out, int out_size, void* d_ws, size_t ws_size,
                              hipStream_t stream) {
    const float* x         = (const float*)d_in[0];
    const float* rel_pos   = (const float*)d_in[1];
    const float* in_proj_w = (const float*)d_in[2];
    const float* in_proj_b = (const float*)d_in[3];
    const float* out_w     = (const float*)d_in[4];
    const float* out_b     = (const float*)d_in[5];
    const float* w1        = (const float*)d_in[6];
    const float* b1        = (const float*)d_in[7];
    const float* w2        = (const float*)d_in[8];
    const float* b2        = (const float*)d_in[9];
    const float* ln1_g     = (const float*)d_in[10];
    const float* ln1_b     = (const float*)d_in[11];
    const float* ln2_g     = (const float*)d_in[12];
    const float* ln2_b     = (const float*)d_in[13];
    float* out = (float*)d_out;

    char* wsb = (char*)d_ws;
    const size_t MB = 1024 * 1024;
    unsigned short* wqkv_b = (unsigned short*)(wsb + 0);        // 6 MB
    unsigned short* wout_b = (unsigned short*)(wsb + 6 * MB);   // 2 MB
    unsigned short* w1_b   = (unsigned short*)(wsb + 8 * MB);   // 8 MB
    unsigned short* w2_b   = (unsigned short*)(wsb + 16 * MB);  // 8 MB
    unsigned short* xn_b   = (unsigned short*)(wsb + 24 * MB);  // 8 MB (xn, then xm)
    unsigned short* qkv_b  = (unsigned short*)(wsb + 32 * MB);  // 24 MB
    unsigned short* h_b    = (unsigned short*)(wsb + 32 * MB);  // 32 MB (reuses qkv+o)
    unsigned short* o_b    = (unsigned short*)(wsb + 56 * MB);  // 8 MB

    const int Mrows = BB * NN;   // 4096

    // all four weight conversions in one launch (3145728 float4s)
    f2bf_all_kernel<<<3 * EE * EE / 256, 256, 0, stream>>>(
        in_proj_w, out_w, w1, w2, wqkv_b, wout_b, w1_b, w2_b);

    ln_kernel<<<Mrows, 256, 0, stream>>>(x, ln1_g, ln1_b, xn_b);
    // QKV: 128^2 TLP kernel, grid 24x32 = 768 blocks (3/CU, 12 waves/CU)
    gemm97t_kernel<0><<<dim3(3 * EE / 128, Mrows / 128), 256, 0, stream>>>(
        xn_b, wqkv_b, in_proj_b, qkv_b, 3 * EE, EE);
    attn_mfma_kernel<<<dim3(NN / 64, HH, BB), 256, 0, stream>>>(qkv_b, rel_pos, o_b);
    // out-proj + residual: K-half kernel (grid-capped 8x32 = 256 blocks)
    gemm_kh_kernel<<<dim3(EE / 128, Mrows / 128), 512, 0, stream>>>(
        o_b, wout_b, out_b, x, out, EE, EE);
    ln_kernel<<<Mrows, 256, 0, stream>>>(out, ln2_g, ln2_b, xn_b);
    // FFN1: 128^2 TLP kernel, grid 32x32 = 1024 blocks (3/CU resident), relu
    gemm97t_kernel<1><<<dim3(4 * EE / 128, Mrows / 128), 256, 0, stream>>>(
        xn_b, w1_b, b1, h_b, 4 * EE, EE);
    // FFN2 + residual (in-place on d_out): K-half kernel, grid 8x32
    gemm_kh_kernel<<<dim3(EE / 128, Mrows / 128), 512, 0, stream>>>(
        h_b, w2_b, b2, out, out, EE, 4 * EE);
}